// Round 4
// baseline (613.539 us; speedup 1.0000x reference)
//
#include <hip/hip_runtime.h>

#define B_  64
#define S_  128
#define H_  8
#define D_  64
#define HID 512
#define G_  8

typedef short short8 __attribute__((ext_vector_type(8)));
typedef float f32x4 __attribute__((ext_vector_type(4)));

__device__ __forceinline__ float bf2f(unsigned short h) {
    union { unsigned int u; float f; } v; v.u = (unsigned int)h << 16; return v.f;
}
__device__ __forceinline__ unsigned short f2bf(float f) {
    union { float f; unsigned int u; } v; v.f = f;
    unsigned int r = v.u + 0x7fffu + ((v.u >> 16) & 1u);
    return (unsigned short)(r >> 16);
}
__device__ __forceinline__ unsigned int cvt_pk_bf16(float lo, float hi) {
    unsigned int r;
    asm("v_cvt_pk_bf16_f32 %0, %1, %2" : "=v"(r) : "v"(lo), "v"(hi));
    return r;
}

// ---- transpose f32 [dim][dim] (in,out) -> bf16 [dim][dim] (out,in) ----
__global__ __launch_bounds__(256) void wtrans(const float* __restrict__ s0,
                                              const float* __restrict__ s1,
                                              const float* __restrict__ s2,
                                              unsigned short* __restrict__ dst0, int dim)
{
    const float* srcs[3] = {s0, s1, s2};
    const float* src = srcs[blockIdx.z];
    unsigned short* dst = dst0 + (size_t)blockIdx.z * dim * dim;
    __shared__ float tile[32][33];
    const int tx = threadIdx.x & 31, ty = threadIdx.x >> 5;
    const int k0 = blockIdx.x * 32, n0 = blockIdx.y * 32;
    #pragma unroll
    for (int r = 0; r < 4; ++r) {
        int row = ty + r * 8;
        tile[row][tx] = src[(size_t)(k0 + row) * dim + n0 + tx];
    }
    __syncthreads();
    #pragma unroll
    for (int r = 0; r < 4; ++r) {
        int row = ty + r * 8;
        dst[(size_t)(n0 + row) * dim + k0 + tx] = f2bf(tile[tx][row]);
    }
}

// ---- QKV projection: bf16 MFMA GEMM; Q/K head-major, V as VT[b,h,e,j] ----
__global__ __launch_bounds__(256) void qkv_mfma(
    const float* __restrict__ hidden,
    const unsigned short* __restrict__ wt,
    const float* __restrict__ bq, const float* __restrict__ bk, const float* __restrict__ bv,
    unsigned short* __restrict__ Qb,   // [B][H][S][D]
    unsigned short* __restrict__ Kb,   // [B][H][S][D]
    unsigned short* __restrict__ VT)   // [B][H][D][S]
{
    const int z = blockIdx.z;
    const unsigned short* W = wt + (size_t)z * HID * HID;
    const float* bias = (z == 0) ? bq : (z == 1) ? bk : bv;
    const int bm = blockIdx.y * 128, bn = blockIdx.x * 128;
    const int t = threadIdx.x, lane = t & 63, w = t >> 6, grp = lane >> 4, l15 = lane & 15;

    __shared__ unsigned short a_s[128 * 72];
    __shared__ unsigned short b_s[128 * 72];

    f32x4 acc[2][8];
    #pragma unroll
    for (int i = 0; i < 2; ++i)
        #pragma unroll
        for (int j = 0; j < 8; ++j) acc[i][j] = (f32x4){0.f, 0.f, 0.f, 0.f};

    for (int k0 = 0; k0 < HID; k0 += 64) {
        #pragma unroll
        for (int it = 0; it < 8; ++it) {
            int idx = t + it * 256;
            int row = idx >> 4, c = idx & 15;
            float4 v4 = *reinterpret_cast<const float4*>(&hidden[(size_t)(bm + row) * HID + k0 + c * 4]);
            unsigned int lo = cvt_pk_bf16(v4.x, v4.y);
            unsigned int hi = cvt_pk_bf16(v4.z, v4.w);
            *reinterpret_cast<uint2*>(&a_s[row * 72 + c * 4]) = make_uint2(lo, hi);
        }
        #pragma unroll
        for (int it = 0; it < 4; ++it) {
            int idx = t + it * 256;
            int row = idx >> 3, c = idx & 7;
            *reinterpret_cast<short8*>(&b_s[row * 72 + c * 8]) =
                *reinterpret_cast<const short8*>(&W[(size_t)(bn + row) * HID + k0 + c * 8]);
        }
        __syncthreads();
        short8 af[2][2];
        #pragma unroll
        for (int mt = 0; mt < 2; ++mt)
            #pragma unroll
            for (int kk = 0; kk < 2; ++kk)
                af[mt][kk] = *reinterpret_cast<const short8*>(&a_s[(w * 32 + mt * 16 + l15) * 72 + kk * 32 + grp * 8]);
        #pragma unroll
        for (int nt = 0; nt < 8; ++nt) {
            short8 b0 = *reinterpret_cast<const short8*>(&b_s[(nt * 16 + l15) * 72 + grp * 8]);
            short8 b1 = *reinterpret_cast<const short8*>(&b_s[(nt * 16 + l15) * 72 + 32 + grp * 8]);
            #pragma unroll
            for (int mt = 0; mt < 2; ++mt) {
                acc[mt][nt] = __builtin_amdgcn_mfma_f32_16x16x32_bf16(af[mt][0], b0, acc[mt][nt], 0, 0, 0);
                acc[mt][nt] = __builtin_amdgcn_mfma_f32_16x16x32_bf16(af[mt][1], b1, acc[mt][nt], 0, 0, 0);
            }
        }
        __syncthreads();
    }
    unsigned short* dstqk = (z == 0) ? Qb : Kb;
    #pragma unroll
    for (int nt = 0; nt < 8; ++nt) {
        int col = bn + nt * 16 + l15;
        float bval = bias[col];
        #pragma unroll
        for (int mt = 0; mt < 2; ++mt) {
            #pragma unroll
            for (int r = 0; r < 4; ++r) {
                int row = bm + w * 32 + mt * 16 + grp * 4 + r;
                unsigned short val = f2bf(acc[mt][nt][r] + bval);
                int bb = row >> 7, jj = row & 127, hh = col >> 6, dd = col & 63;
                if (z == 2) {
                    VT[(((size_t)bb * H_ + hh) * D_ + dd) * S_ + jj] = val;
                } else {
                    dstqk[(((size_t)bb * H_ + hh) * S_ + jj) * D_ + dd] = val;
                }
            }
        }
    }
}

// ---- sc0[b,h,i,j] = sum_d K[b,h,i,d] * Q[b,h,j,d], stored bf16 ----
__global__ __launch_bounds__(256) void kq_gemm(
    const unsigned short* __restrict__ Kb, const unsigned short* __restrict__ Qb,
    unsigned short* __restrict__ sc0)
{
    const int bh = blockIdx.x;
    const int t = threadIdx.x, lane = t & 63, w = t >> 6, grp = lane >> 4, l15 = lane & 15;
    const unsigned short* Kp = Kb + (size_t)bh * S_ * D_;
    const unsigned short* Qp = Qb + (size_t)bh * S_ * D_;
    unsigned short* outp = sc0 + (size_t)bh * S_ * S_;
    short8 af[2][2];
    #pragma unroll
    for (int mt = 0; mt < 2; ++mt)
        #pragma unroll
        for (int kk = 0; kk < 2; ++kk)
            af[mt][kk] = *reinterpret_cast<const short8*>(&Kp[(size_t)(w * 32 + mt * 16 + l15) * D_ + kk * 32 + grp * 8]);
    #pragma unroll
    for (int nt = 0; nt < 8; ++nt) {
        short8 b0 = *reinterpret_cast<const short8*>(&Qp[(size_t)(nt * 16 + l15) * D_ + grp * 8]);
        short8 b1 = *reinterpret_cast<const short8*>(&Qp[(size_t)(nt * 16 + l15) * D_ + 32 + grp * 8]);
        #pragma unroll
        for (int mt = 0; mt < 2; ++mt) {
            f32x4 a = {0.f, 0.f, 0.f, 0.f};
            a = __builtin_amdgcn_mfma_f32_16x16x32_bf16(af[mt][0], b0, a, 0, 0, 0);
            a = __builtin_amdgcn_mfma_f32_16x16x32_bf16(af[mt][1], b1, a, 0, 0, 0);
            #pragma unroll
            for (int r = 0; r < 4; ++r)
                outp[(size_t)(w * 32 + mt * 16 + grp * 4 + r) * S_ + nt * 16 + l15] = f2bf(a[r]);
        }
    }
}

// ---- fused structure-proj + scores + PV/PSV; block per (b, 8 i's) ----
// LDS: 0 stks[128][64]s(swz)  16384 sq[128][64]s(swz)  32768 svT[64][128]s(swz, 256B rows)
//      49152 k_s[16][64]s(swz)/p_bf[8][128]s  51200 kqs[8][128]s  53248 rsp[16]f
__global__ __launch_bounds__(256) void attn3(
    const unsigned short* __restrict__ Qb, const unsigned short* __restrict__ Kb,
    const unsigned short* __restrict__ VT,
    const unsigned short* __restrict__ sc0,
    const float* __restrict__ st, const float* __restrict__ mask,
    const unsigned short* __restrict__ wtS,
    const float* __restrict__ bsq, const float* __restrict__ bsk, const float* __restrict__ bsv,
    float* __restrict__ out)
{
    const int flat = blockIdx.y * gridDim.x + blockIdx.x;     // 0..1023
    const int swz  = (flat & 7) * 128 + (flat >> 3);          // XCD-contiguous
    const int b  = swz >> 4;
    const int ig = swz & 15;
    const int t = threadIdx.x, lane = t & 63, w = t >> 6, grp = lane >> 4, l15 = lane & 15;

    __shared__ __align__(16) unsigned char smem[53312];
    float* rsp = (float*)(smem + 53248);

    const float* stbase = st + (size_t)b * S_ * S_ * D_;
    float4 stg[8];
    {   // prologue: issue loads for i0
        const float* p = stbase + (size_t)(ig * G_) * (S_ * D_);
        #pragma unroll
        for (int l = 0; l < 8; ++l)
            stg[l] = *reinterpret_cast<const float4*>(p + (size_t)(t + l * 256) * 4);
    }

    for (int it = 0; it < G_; ++it) {
        const int i = ig * G_ + it;

        // ---- 1: convert staged regs -> st LDS (swizzled) ----
        #pragma unroll
        for (int l = 0; l < 8; ++l) {
            const int idx = t + l * 256;
            const int row = idx >> 4, c = idx & 15;
            unsigned int lo = cvt_pk_bf16(stg[l].x, stg[l].y);
            unsigned int hi = cvt_pk_bf16(stg[l].z, stg[l].w);
            *reinterpret_cast<uint2*>((char*)smem + row * 128 + ((((c >> 1) ^ (row & 7)) << 4)) + 8 * (c & 1))
                = make_uint2(lo, hi);
        }
        __syncthreads();

        // ---- 3: hoist A-frags to regs ----
        short8 af[2][2];
        #pragma unroll
        for (int mt = 0; mt < 2; ++mt) {
            const int row = w * 32 + mt * 16 + l15, rs = row & 7;
            af[mt][0] = *reinterpret_cast<const short8*>((const char*)smem + row * 128 + ((grp ^ rs) << 4));
            af[mt][1] = *reinterpret_cast<const short8*>((const char*)smem + row * 128 + (((4 + grp) ^ rs) << 4));
        }
        __syncthreads();

        // ---- 5: prefetch next st tile into regs; stage k_i; projections ----
        if (it + 1 < G_) {
            const float* nxt = stbase + (size_t)(i + 1) * (S_ * D_);
            #pragma unroll
            for (int l = 0; l < 8; ++l)
                stg[l] = *reinterpret_cast<const float4*>(nxt + (size_t)(t + l * 256) * 4);
        }
        if (t < 64) {
            const int h = t >> 3, c = t & 7;
            short8 kv = *reinterpret_cast<const short8*>(&Kb[(((size_t)b * H_ + h) * S_ + i) * D_ + c * 8]);
            *reinterpret_cast<short8*>((char*)smem + 49152 + h * 128 + (((c ^ (h & 7)) << 4))) = kv;
        }
        {
            #pragma unroll
            for (int p = 0; p < 3; ++p) {
                const unsigned short* Wp = wtS + p * (D_ * D_);
                const float* bsp = (p == 0) ? bsq : (p == 1) ? bsk : bsv;
                #pragma unroll
                for (int nt = 0; nt < 4; ++nt) {
                    short8 bf0 = *reinterpret_cast<const short8*>(&Wp[(size_t)(nt * 16 + l15) * D_ + grp * 8]);
                    short8 bf1 = *reinterpret_cast<const short8*>(&Wp[(size_t)(nt * 16 + l15) * D_ + 32 + grp * 8]);
                    float bval = bsp[nt * 16 + l15];
                    #pragma unroll
                    for (int mt = 0; mt < 2; ++mt) {
                        f32x4 a = (f32x4){0.f, 0.f, 0.f, 0.f};
                        a = __builtin_amdgcn_mfma_f32_16x16x32_bf16(af[mt][0], bf0, a, 0, 0, 0);
                        a = __builtin_amdgcn_mfma_f32_16x16x32_bf16(af[mt][1], bf1, a, 0, 0, 0);
                        const int jrow = w * 32 + mt * 16 + grp * 4;
                        if (p == 2) {   // SV transposed -> svT[e][j], 256B rows
                            const int e = nt * 16 + l15;
                            unsigned int lo = cvt_pk_bf16(a[0] + bval, a[1] + bval);
                            unsigned int hi = cvt_pk_bf16(a[2] + bval, a[3] + bval);
                            const int slot = (4 * w + 2 * mt + (grp >> 1)) ^ (e & 7);
                            *reinterpret_cast<uint2*>((char*)smem + 32768 + (e << 8) + (slot << 4) + 8 * (grp & 1))
                                = make_uint2(lo, hi);
                        } else {        // SQ -> sq_s, SK -> stks (overlay st)
                            char* oB = (char*)smem + (p == 0 ? 16384 : 0);
                            #pragma unroll
                            for (int r = 0; r < 4; ++r) {
                                const int row = jrow + r;
                                const int slot = (2 * nt + (l15 >> 3)) ^ (row & 7);
                                *reinterpret_cast<unsigned short*>(oB + row * 128 + (slot << 4) + ((2 * l15) & 15))
                                    = f2bf(a[r] + bval);
                            }
                        }
                    }
                }
            }
        }
        __syncthreads();

        // ---- 7: ksq[h,j] = k_i . sq_j  (MFMA, rows 8-15 garbage/discarded) ----
        {
            const char* kB = (const char*)smem + 49152;
            const int ks = l15 & 7;
            short8 ka0 = *reinterpret_cast<const short8*>(kB + l15 * 128 + ((grp ^ ks) << 4));
            short8 ka1 = *reinterpret_cast<const short8*>(kB + l15 * 128 + (((4 + grp) ^ ks) << 4));
            unsigned short* kqs = (unsigned short*)(smem + 51200);
            const char* sqB = (const char*)smem + 16384;
            #pragma unroll
            for (int nt2 = 0; nt2 < 2; ++nt2) {
                const int j0 = w * 32 + nt2 * 16;
                const int row = j0 + l15, rs = row & 7;
                short8 b0 = *reinterpret_cast<const short8*>(sqB + row * 128 + ((grp ^ rs) << 4));
                short8 b1 = *reinterpret_cast<const short8*>(sqB + row * 128 + (((4 + grp) ^ rs) << 4));
                f32x4 a = (f32x4){0.f, 0.f, 0.f, 0.f};
                a = __builtin_amdgcn_mfma_f32_16x16x32_bf16(ka0, b0, a, 0, 0, 0);
                a = __builtin_amdgcn_mfma_f32_16x16x32_bf16(ka1, b1, a, 0, 0, 0);
                if (grp < 2) {
                    #pragma unroll
                    for (int r = 0; r < 4; ++r)
                        kqs[(grp * 4 + r) * S_ + j0 + l15] = f2bf(a[r]);
                }
            }
        }
        __syncthreads();

        // ---- 9: scores -> p (bf16, unnormalized) + rowsums ----
        {
            const int jj = (w & 1) * 64 + lane;
            const int hg = w >> 1;
            const int jsw = jj & 7;
            const char* skB = (const char*)smem + jj * 128;
            const char* sqB = (const char*)smem + 16384 + jj * 128;
            const unsigned short* qp = Qb + (((size_t)b * H_ + hg * 4) * S_ + jj) * D_;
            float a0 = 0.f, a1 = 0.f, a2 = 0.f, a3 = 0.f, ss = 0.f;
            #pragma unroll
            for (int c = 0; c < 8; ++c) {
                const int off = (c ^ jsw) << 4;
                short8 sk8 = *reinterpret_cast<const short8*>(skB + off);
                short8 sq8 = *reinterpret_cast<const short8*>(sqB + off);
                short8 q0 = *reinterpret_cast<const short8*>(&qp[c * 8]);
                short8 q1 = *reinterpret_cast<const short8*>(&qp[S_ * D_ + c * 8]);
                short8 q2 = *reinterpret_cast<const short8*>(&qp[2 * S_ * D_ + c * 8]);
                short8 q3 = *reinterpret_cast<const short8*>(&qp[3 * S_ * D_ + c * 8]);
                #pragma unroll
                for (int e = 0; e < 8; ++e) {
                    float skf = bf2f((unsigned short)sk8[e]);
                    float sqf = bf2f((unsigned short)sq8[e]);
                    a0 += bf2f((unsigned short)q0[e]) * skf;
                    a1 += bf2f((unsigned short)q1[e]) * skf;
                    a2 += bf2f((unsigned short)q2[e]) * skf;
                    a3 += bf2f((unsigned short)q3[e]) * skf;
                    ss += skf * sqf;
                }
            }
            const float mv = mask[((size_t)b * S_ + i) * S_ + jj];
            const unsigned short* s0p = sc0 + (((size_t)b * H_ + hg * 4) * S_ + i) * S_ + jj;
            const unsigned short* kqs = (const unsigned short*)(smem + 51200);
            unsigned short* pbf = (unsigned short*)(smem + 49152);
            float qsk[4] = {a0, a1, a2, a3};
            #pragma unroll
            for (int hh = 0; hh < 4; ++hh) {
                const int h = hg * 4 + hh;
                float kqv  = bf2f(s0p[(size_t)hh * S_ * S_]);
                float ksqv = bf2f(kqs[h * S_ + jj]);
                float s = (kqv + ksqv + qsk[hh] + ss) * 0.125f + mv;
                float pv = fmaxf(s, 0.f);
                pbf[h * S_ + jj] = f2bf(pv);
                float r = pv;
                #pragma unroll
                for (int o2 = 1; o2 < 64; o2 <<= 1) r += __shfl_xor(r, o2);
                if (lane == 0) rsp[w * 4 + hh] = r;
            }
        }
        __syncthreads();

        // ---- 13: PV + PSV via broadcast-A MFMA; normalize in epilogue ----
        {
            #pragma unroll
            for (int hh = 0; hh < 2; ++hh) {
                const int h = w + hh * 4;
                const unsigned short* pb = (const unsigned short*)(smem + 49152) + h * S_;
                short8 pa[4];
                #pragma unroll
                for (int kk = 0; kk < 4; ++kk)
                    pa[kk] = *reinterpret_cast<const short8*>(&pb[kk * 32 + grp * 8]);
                const float den = rsp[hh * 8 + w] + rsp[hh * 8 + 4 + w] + 1.28e-10f;
                const float inv = 1.0f / den;
                const unsigned short* vtb = VT + ((size_t)b * H_ + h) * (D_ * S_);
                #pragma unroll
                for (int nt = 0; nt < 4; ++nt) {
                    const int e = nt * 16 + l15, es = e & 7;
                    const char* svRow = (const char*)smem + 32768 + (e << 8);
                    f32x4 a = (f32x4){0.f, 0.f, 0.f, 0.f};
                    #pragma unroll
                    for (int kk = 0; kk < 4; ++kk)
                        a = __builtin_amdgcn_mfma_f32_16x16x32_bf16(
                            pa[kk], *reinterpret_cast<const short8*>(&vtb[(size_t)e * S_ + kk * 32 + grp * 8]), a, 0, 0, 0);
                    #pragma unroll
                    for (int kk = 0; kk < 4; ++kk)
                        a = __builtin_amdgcn_mfma_f32_16x16x32_bf16(
                            pa[kk], *reinterpret_cast<const short8*>(svRow + (((4 * kk + grp) ^ es) << 4)), a, 0, 0, 0);
                    if (grp == 0)
                        out[((size_t)b * S_ + i) * HID + h * D_ + nt * 16 + l15] = a[0] * inv;
                }
            }
        }
        // no trailing barrier needed: phase-13 reads (svT/pbf/rsp) are disjoint
        // from next iter's phase-1 writes (st region); later overlaps are
        // ordered by the phase-1 and phase-3 barriers.
    }
}

extern "C" void kernel_launch(void* const* d_in, const int* in_sizes, int n_in,
                              void* d_out, int out_size, void* d_ws, size_t ws_size,
                              hipStream_t stream) {
    const float* hidden = (const float*)d_in[0];
    const float* mask   = (const float*)d_in[1];
    const float* st     = (const float*)d_in[2];
    const float* Wq  = (const float*)d_in[3];
    const float* bq  = (const float*)d_in[4];
    const float* Wk  = (const float*)d_in[5];
    const float* bk  = (const float*)d_in[6];
    const float* Wv  = (const float*)d_in[7];
    const float* bv  = (const float*)d_in[8];
    const float* Wsq = (const float*)d_in[9];
    const float* bsq = (const float*)d_in[10];
    const float* Wsk = (const float*)d_in[11];
    const float* bsk = (const float*)d_in[12];
    const float* Wsv = (const float*)d_in[13];
    const float* bsv = (const float*)d_in[14];
    float* out = (float*)d_out;

    unsigned char* ws = (unsigned char*)d_ws;
    unsigned short* wtB = (unsigned short*)(ws);                 // 1572864 B
    unsigned short* wtS = (unsigned short*)(ws + 1572864);       // 24576 B
    unsigned short* Qb  = (unsigned short*)(ws + 1597440);       // 8388608 B
    unsigned short* Kb  = (unsigned short*)(ws + 9986048);       // 8388608 B
    unsigned short* VT  = (unsigned short*)(ws + 18374656);      // 8388608 B
    unsigned short* sc0 = (unsigned short*)(ws + 26763264);      // 16777216 B

    wtrans<<<dim3(16, 16, 3), 256, 0, stream>>>(Wq, Wk, Wv, wtB, 512);
    wtrans<<<dim3(2, 2, 3), 256, 0, stream>>>(Wsq, Wsk, Wsv, wtS, 64);
    qkv_mfma<<<dim3(4, 64, 3), 256, 0, stream>>>(hidden, wtB, bq, bk, bv, Qb, Kb, VT);
    kq_gemm<<<dim3(512), 256, 0, stream>>>(Kb, Qb, sc0);
    attn3<<<dim3(16, 64), 256, 0, stream>>>(Qb, Kb, VT, sc0, st, mask, wtS, bsq, bsk, bsv, out);
}